// Round 3
// baseline (9521.024 us; speedup 1.0000x reference)
//
#include <hip/hip_runtime.h>
#include <hip/hip_bf16.h>
#include <math.h>

// Problem constants
#define SEQL   4096
#define NITEMS 512
#define HID    256
#define NLAY   16
#define QS     64      // ring slots (power of 2)
#define TPB    4       // timesteps per block in proj kernel

typedef float f4 __attribute__((ext_vector_type(4)));
typedef float f2 __attribute__((ext_vector_type(2)));

// Workspace layout (float offsets)
#define P_OFF   ((size_t)0)                               // P[4][SEQL][HID]
#define H_OFF   (P_OFF + (size_t)4*SEQL*HID)              // Hring[4][NLAY][QS][HID]
#define AP_OFF  (H_OFF + (size_t)4*NLAY*QS*HID)           // Apart[4][NLAY][QS][HID]
#define HF_OFF  (AP_OFF + (size_t)4*NLAY*QS*HID)          // hfinal[4][HID]
#define FLAG_OFF_FLOATS (HF_OFF + (size_t)1024)
// flags: Hflag[64] | Aflag[64] | progA[64] | progB[64]  => 256 u32
#define NFLAGS 256

// ---------------------------------------------------------------------------
// Coherent (IF$-level, sc0 sc1) vector memory ops as inline asm so WE control
// the vmcnt ledger. All volatile -> mutual program order preserved.
__device__ __forceinline__ f4 ld_coh_f4(const float* p) {
    f4 r;
    asm volatile("global_load_dwordx4 %0, %1, off sc0 sc1" : "=v"(r) : "v"(p));
    return r;
}
__device__ __forceinline__ f4 ld_plain_f4(const float* p) {
    f4 r;
    asm volatile("global_load_dwordx4 %0, %1, off" : "=v"(r) : "v"(p));
    return r;
}
__device__ __forceinline__ void st_coh_f4(float* p, f4 v) {
    asm volatile("global_store_dwordx4 %0, %1, off sc0 sc1" :: "v"(p), "v"(v) : "memory");
}
__device__ __forceinline__ void st_coh_u32(unsigned* p, unsigned v) {
    asm volatile("global_store_dword %0, %1, off sc0 sc1" :: "v"(p), "v"(v) : "memory");
}
__device__ __forceinline__ unsigned uload(const unsigned* p) {
    return __hip_atomic_load(p, __ATOMIC_RELAXED, __HIP_MEMORY_SCOPE_AGENT);
}
__device__ __forceinline__ void ustore(unsigned* p, unsigned v) {
    __hip_atomic_store(p, v, __ATOMIC_RELAXED, __HIP_MEMORY_SCOPE_AGENT);
}

#define SBAR()  { __builtin_amdgcn_s_barrier(); __builtin_amdgcn_sched_barrier(0); }
#define LGKM0() { asm volatile("s_waitcnt lgkmcnt(0)" ::: "memory"); __builtin_amdgcn_sched_barrier(0); }
#define VMW(N)  { asm volatile("s_waitcnt vmcnt(" #N ")" ::: "memory"); __builtin_amdgcn_sched_barrier(0); }

// Spin until *p >= target. Sticky timeout -> bugs give wrong answers, not hangs.
__device__ __forceinline__ unsigned spin_ge(const unsigned* p, unsigned target, bool* dead) {
    unsigned v = uload(p);
    if (v >= target || *dead) return v;
    unsigned it = 0;
    while ((v = uload(p)) < target) {
        __builtin_amdgcn_s_sleep(1);
        if (++it > (1u << 20)) { *dead = true; break; }
    }
    return v;
}

// FMA phase: every thread, 64 MACs from LDS-broadcast h times register weights.
__device__ __forceinline__ void fma_phase(const float* hbase, const f4* w,
                                          float* part, int tid, int c4) {
    f2 acc = (f2)0.f;
    const f4* hb4 = (const f4*)hbase;
    #pragma unroll
    for (int i = 0; i < 16; ++i) {
        f4 v = hb4[c4 * 16 + i];
        f4 wi = w[i];
        acc = wi.xy * v.xy + acc;
        acc = wi.zw * v.zw + acc;
    }
    part[tid] = acc.x + acc.y;
}

// ---------------------------------------------------------------------------
// Kernel 1: input projection P[c][t][j] = sum_k Wih0_c[j,k] * x[t,k,c]
__global__ __launch_bounds__(1024) void proj_kernel(
    const float* __restrict__ x, const float* __restrict__ Wlp,
    const float* __restrict__ Wlpv, float* __restrict__ P)
{
    __shared__ float xs[TPB][4][NITEMS];   // 32 KB
    const int tid = threadIdx.x;
    const int t0 = blockIdx.x * TPB;

    #pragma unroll
    for (int tt = 0; tt < TPB; ++tt) {
        const float2* src = (const float2*)(x + (size_t)(t0 + tt) * NITEMS * 4);
        float2 v = src[tid];
        int e = 2 * tid;
        xs[tt][e & 3][e >> 2]       = v.x;
        xs[tt][(e + 1) & 3][e >> 2] = v.y;
    }
    __syncthreads();

    const int c = tid >> 8, j = tid & 255;
    const float* W = (c == 1) ? Wlpv : Wlp;
    const float4* row = (const float4*)(W + (size_t)j * NITEMS);
    float acc[TPB] = {0.f, 0.f, 0.f, 0.f};
    #pragma unroll 4
    for (int k4 = 0; k4 < NITEMS / 4; ++k4) {
        float4 w = row[k4];
        #pragma unroll
        for (int tt = 0; tt < TPB; ++tt) {
            float4 xv = *(const float4*)(&xs[tt][c][k4 * 4]);
            acc[tt] = fmaf(w.x, xv.x, fmaf(w.y, xv.y, fmaf(w.z, xv.z, fmaf(w.w, xv.w, acc[tt]))));
        }
    }
    #pragma unroll
    for (int tt = 0; tt < TPB; ++tt)
        P[((size_t)c * SEQL + (t0 + tt)) * HID + j] = acc[tt];
}

// ---------------------------------------------------------------------------
// One B timestep. Wave0 vmem ledger per step: S(t), L(t+2), F(t-1).
// VN: steady 2 (keeps {L(t+1),F(t-2)}, drains L(t) & S(t-1)); peel 1,1; tail 0.
#define B_STEP(T_, AREG, VN) {                                                  \
    const int t_ = (T_);                                                        \
    fma_phase(hhA[0], w, part, tid, c4);                                        \
    if (tid == 64) {                                                            \
        if (has_af && t_ + 2 < SEQL) spin_ge(af, (unsigned)(t_ + 3), &dead);    \
        if ((t_ & 7) == 0 && t_ >= QS) spin_ge(consProgA, (unsigned)(t_ - 56), &dead); \
    }                                                                           \
    if (tid == 65 && has_af && (t_ & 7) == 0 && t_ > 0)                         \
        ustore(myprogB, (unsigned)t_);                                          \
    LGKM0(); SBAR();                                                            \
    if (tid < 64) {                                                             \
        VMW(VN);                                                                \
        const f4* pq = (const f4*)part;                                         \
        f4 s = pq[tid] + pq[64 + tid] + pq[128 + tid] + pq[192 + tid];          \
        f4 tot = s + AREG + bias4;                                              \
        f4 h4;                                                                  \
        h4.x = tanhf(tot.x); h4.y = tanhf(tot.y);                               \
        h4.z = tanhf(tot.z); h4.w = tanhf(tot.w);                               \
        ((f4*)hhA[0])[tid] = h4;                                                \
        st_coh_f4(Hout + (size_t)(t_ & (QS - 1)) * HID + 4 * tid, h4);          \
        if (is_top && t_ == SEQL - 1) *(f4*)(hfin + 4 * tid) = h4;              \
        if (t_ + 2 < SEQL) {                                                    \
            AREG = l0 ? ld_plain_f4(Psrc + (size_t)(t_ + 2) * HID + 4 * tid)    \
                      : ld_coh_f4(ap + (size_t)((t_ + 2) & (QS - 1)) * HID + 4 * tid); \
        }                                                                       \
        LGKM0();                                                                \
    }                                                                           \
    SBAR();                                                                     \
    if (tid == 0 && t_ > 0) st_coh_u32(myHfl, (unsigned)t_);                    \
}

// One A timestep. Ledger identical: S(t), L(t+3), F(t-1). Consumes L(t+1).
#define A_STEP(T_, PREG, VN) {                                                  \
    const int t_ = (T_);                                                        \
    fma_phase(hhA[(T_) & 1], w, part, tid, c4);                                 \
    if (tid == 64) {                                                            \
        if (t_ + 3 < SEQL) spin_ge(inflag, (unsigned)(t_ + 4), &dead);          \
        if ((t_ & 7) == 0 && t_ >= QS) spin_ge(consProgB, (unsigned)(t_ - 56), &dead); \
    }                                                                           \
    if (tid == 65 && (t_ & 7) == 0 && t_ > 0)                                   \
        ustore(myprogA, (unsigned)t_);                                          \
    LGKM0(); SBAR();                                                            \
    if (tid < 64) {                                                             \
        VMW(VN);                                                                \
        const f4* pq = (const f4*)part;                                         \
        f4 s = pq[tid] + pq[64 + tid] + pq[128 + tid] + pq[192 + tid];          \
        st_coh_f4(Aout + (size_t)(t_ & (QS - 1)) * HID + 4 * tid, s);           \
        if (t_ + 1 < SEQL) ((f4*)hhA[(t_ + 1) & 1])[tid] = PREG;                \
        if (t_ + 3 < SEQL)                                                      \
            PREG = ld_coh_f4(Hin + (size_t)((t_ + 3) & (QS - 1)) * HID + 4 * tid); \
        LGKM0();                                                                \
    }                                                                           \
    SBAR();                                                                     \
    if (tid == 0 && t_ > 0) st_coh_u32(myAfl, (unsigned)t_);                    \
}

// ---------------------------------------------------------------------------
// Kernel 2: layer-pipelined RNN. 124 blocks = 4 chains x (16 B + 15 A).
__global__ __launch_bounds__(1024) void rnn_pipe(
    const float* __restrict__ lp_Wih,  const float* __restrict__ lp_Whh,
    const float* __restrict__ lp_bih,  const float* __restrict__ lp_bhh,
    const float* __restrict__ lpv_Wih, const float* __restrict__ lpv_Whh,
    const float* __restrict__ lpv_bih, const float* __restrict__ lpv_bhh,
    const float* __restrict__ P, float* __restrict__ Hring,
    float* __restrict__ Apart, float* __restrict__ hfinal,
    unsigned* __restrict__ Hflag, unsigned* __restrict__ Aflag,
    unsigned* __restrict__ progA, unsigned* __restrict__ progB)
{
    __shared__ float hhA[2][HID];
    __shared__ float part[1024];

    const int b = blockIdx.x;
    if (b >= 124) return;
    const int c = b / 31;
    const int r = b % 31;
    const int role = (r < NLAY) ? 0 : 1;            // 0 = B, 1 = A
    const int l = (r < NLAY) ? r : (r - NLAY + 1);  // A covers l = 1..15

    const float* Wih = (c == 1) ? lpv_Wih : lp_Wih;
    const float* Whh = (c == 1) ? lpv_Whh : lp_Whh;
    const float* bih = (c == 1) ? lpv_bih : lp_bih;
    const float* bhh = (c == 1) ? lpv_bhh : lp_bhh;

    const int tid = threadIdx.x;
    const int j = tid & 255, c4 = tid >> 8;   // c4 wave-group-uniform
    bool dead = false;

    if (role == 0) {
        // ===================== B role =====================
        const bool l0     = (l == 0);
        const bool has_af = (l > 0);
        const bool is_top = (l == NLAY - 1);

        f4 w[16];
        {
            const f4* wrow = (const f4*)(Whh + ((size_t)l * HID + j) * HID + (size_t)c4 * 64);
            #pragma unroll
            for (int i = 0; i < 16; ++i) w[i] = wrow[i];
        }
        #pragma unroll
        for (int i = 0; i < 16; ++i) asm volatile("" : "+v"(w[i]));

        f4 bias4 = (f4)0.f;
        if (tid < 64) {
            bias4 = *(const f4*)(bih + l * HID + 4 * tid);
            bias4 += *(const f4*)(bhh + l * HID + 4 * tid);
        }

        const float*    Psrc     = P + (size_t)c * SEQL * HID;
        const float*    ap       = Apart + ((size_t)(c * NLAY + l) * QS) * HID;
        const unsigned* af       = Aflag + c * NLAY + l;
        unsigned*       myHfl    = Hflag + c * NLAY + l;
        unsigned*       myprogB  = progB + c * NLAY + l;
        // l==15 has no downstream A; point back-pressure at our own (fresh) progB.
        const unsigned* consProgA = (l < NLAY - 1) ? (progA + c * NLAY + l + 1)
                                                   : (const unsigned*)myprogB;
        float*          Hout     = Hring + ((size_t)(c * NLAY + l) * QS) * HID;
        float*          hfin     = hfinal + (size_t)c * HID;

        // prologue: h(-1)=0; legality for L(0),L(1); issue both prefetches
        if (tid < 256) hhA[0][tid] = 0.f;
        if (has_af && tid == 64) spin_ge(af, 2u, &dead);
        LGKM0(); SBAR();
        f4 a0e = (f4)0.f, a0o = (f4)0.f;
        if (tid < 64) {
            a0e = l0 ? ld_plain_f4(Psrc + 4 * tid)       : ld_coh_f4(ap + 4 * tid);
            a0o = l0 ? ld_plain_f4(Psrc + HID + 4 * tid) : ld_coh_f4(ap + HID + 4 * tid);
        }

        B_STEP(0, a0e, 1);
        B_STEP(1, a0o, 1);
        for (int t2 = 2; t2 < SEQL - 4; t2 += 2) {
            B_STEP(t2,     a0e, 2);
            B_STEP(t2 + 1, a0o, 2);
        }
        B_STEP(SEQL - 4, a0e, 0);
        B_STEP(SEQL - 3, a0o, 0);
        B_STEP(SEQL - 2, a0e, 0);
        B_STEP(SEQL - 1, a0o, 0);

        if (tid < 64) { VMW(0); }
        SBAR();
        if (tid == 0) st_coh_u32(myHfl, (unsigned)SEQL);
    } else {
        // ===================== A role =====================
        f4 w[16];
        {
            const f4* wrow = (const f4*)(Wih + ((size_t)(l - 1) * HID + j) * HID + (size_t)c4 * 64);
            #pragma unroll
            for (int i = 0; i < 16; ++i) w[i] = wrow[i];
        }
        #pragma unroll
        for (int i = 0; i < 16; ++i) asm volatile("" : "+v"(w[i]));

        const float*    Hin       = Hring + ((size_t)(c * NLAY + (l - 1)) * QS) * HID;
        const unsigned* inflag    = Hflag + c * NLAY + (l - 1);
        float*          Aout      = Apart + ((size_t)(c * NLAY + l) * QS) * HID;
        unsigned*       myAfl     = Aflag + c * NLAY + l;
        unsigned*       myprogA   = progA + c * NLAY + l;
        const unsigned* consProgB = progB + c * NLAY + l;

        // prologue: issue L(0),L(1),L(2); consume L(0) -> hh[0]
        if (tid == 64) spin_ge(inflag, 3u, &dead);
        SBAR();
        f4 pvE = (f4)0.f, pvO = (f4)0.f;
        if (tid < 64) {
            f4 tmp = ld_coh_f4(Hin + 4 * tid);
            pvO = ld_coh_f4(Hin + (size_t)1 * HID + 4 * tid);
            pvE = ld_coh_f4(Hin + (size_t)2 * HID + 4 * tid);
            VMW(2);
            ((f4*)hhA[0])[tid] = tmp;
            LGKM0();
        }
        SBAR();

        A_STEP(0, pvO, 1);
        A_STEP(1, pvE, 1);
        for (int t2 = 2; t2 < SEQL - 4; t2 += 2) {
            A_STEP(t2,     pvO, 2);
            A_STEP(t2 + 1, pvE, 2);
        }
        A_STEP(SEQL - 4, pvO, 0);
        A_STEP(SEQL - 3, pvE, 0);
        A_STEP(SEQL - 2, pvO, 0);
        A_STEP(SEQL - 1, pvE, 0);

        if (tid < 64) { VMW(0); }
        SBAR();
        if (tid == 0) st_coh_u32(myAfl, (unsigned)SEQL);
    }
}

// ---------------------------------------------------------------------------
// Kernel 3: out = fc_W @ concat(h0..h3) + fc_b
__global__ __launch_bounds__(1024) void fc_kernel(
    const float* __restrict__ hfinal, const float* __restrict__ fcW,
    const float* __restrict__ fcb, float* __restrict__ out)
{
    __shared__ float red[1024];
    const int tid = threadIdx.x;
    float v  = hfinal[tid];
    float p0 = fcW[tid] * v;
    float p1 = fcW[1024 + tid] * v;

    red[tid] = p0; __syncthreads();
    for (int st = 512; st > 0; st >>= 1) { if (tid < st) red[tid] += red[tid + st]; __syncthreads(); }
    if (tid == 0) out[0] = red[0] + fcb[0];
    __syncthreads();
    red[tid] = p1; __syncthreads();
    for (int st = 512; st > 0; st >>= 1) { if (tid < st) red[tid] += red[tid + st]; __syncthreads(); }
    if (tid == 0) out[1] = red[0] + fcb[1];
}

// ---------------------------------------------------------------------------
extern "C" void kernel_launch(void* const* d_in, const int* in_sizes, int n_in,
                              void* d_out, int out_size, void* d_ws, size_t ws_size,
                              hipStream_t stream)
{
    (void)in_sizes; (void)n_in; (void)out_size; (void)ws_size;
    const float* x        = (const float*)d_in[0];
    const float* lp_Wih0  = (const float*)d_in[1];
    const float* lp_Wih   = (const float*)d_in[2];
    const float* lp_Whh   = (const float*)d_in[3];
    const float* lp_bih   = (const float*)d_in[4];
    const float* lp_bhh   = (const float*)d_in[5];
    const float* lpv_Wih0 = (const float*)d_in[6];
    const float* lpv_Wih  = (const float*)d_in[7];
    const float* lpv_Whh  = (const float*)d_in[8];
    const float* lpv_bih  = (const float*)d_in[9];
    const float* lpv_bhh  = (const float*)d_in[10];
    const float* fcW      = (const float*)d_in[11];
    const float* fcb      = (const float*)d_in[12];

    float* ws      = (float*)d_ws;
    float* Pbuf    = ws + P_OFF;
    float* Hring   = ws + H_OFF;
    float* Apart   = ws + AP_OFF;
    float* hfinal  = ws + HF_OFF;
    unsigned* flags = (unsigned*)(ws + FLAG_OFF_FLOATS);

    hipMemsetAsync(flags, 0, NFLAGS * sizeof(unsigned), stream);

    proj_kernel<<<SEQL / TPB, 1024, 0, stream>>>(x, lp_Wih0, lpv_Wih0, Pbuf);

    rnn_pipe<<<124, 1024, 0, stream>>>(lp_Wih, lp_Whh, lp_bih, lp_bhh,
                                       lpv_Wih, lpv_Whh, lpv_bih, lpv_bhh,
                                       Pbuf, Hring, Apart, hfinal,
                                       flags, flags + 64, flags + 128, flags + 192);

    fc_kernel<<<1, 1024, 0, stream>>>(hfinal, fcW, fcb, (float*)d_out);
}

// Round 4
// 8414.351 us; speedup vs baseline: 1.1315x; 1.1315x over previous
//
#include <hip/hip_runtime.h>
#include <hip/hip_bf16.h>
#include <math.h>

// Problem constants
#define SEQL   4096
#define NITEMS 512
#define HID    256
#define NLAY   16
#define QS     64      // ring slots (power of 2)
#define TPB    4       // timesteps per block in proj kernel

typedef float f4 __attribute__((ext_vector_type(4)));
typedef float f2 __attribute__((ext_vector_type(2)));

// Workspace layout (float offsets)
#define P_OFF   ((size_t)0)                               // P[4][SEQL][HID]
#define H_OFF   (P_OFF + (size_t)4*SEQL*HID)              // Hring[4][NLAY][QS][HID]
#define AP_OFF  (H_OFF + (size_t)4*NLAY*QS*HID)           // Apart[4][NLAY][QS][HID]
#define HF_OFF  (AP_OFF + (size_t)4*NLAY*QS*HID)          // hfinal[4][HID]
#define FLAG_OFF_FLOATS (HF_OFF + (size_t)1024)
// flags: Hflag[64] | Aflag[64] | progA[64] | progB[64]  => 256 u32
#define NFLAGS 256

// ---------------------------------------------------------------------------
// Coherent (IF$-level, sc0 sc1) vector memory ops as inline asm so WE control
// the vmcnt ledger. All volatile -> mutual program order preserved.
__device__ __forceinline__ f4 ld_coh_f4(const float* p) {
    f4 r;
    asm volatile("global_load_dwordx4 %0, %1, off sc0 sc1" : "=v"(r) : "v"(p));
    return r;
}
__device__ __forceinline__ f4 ld_plain_f4(const float* p) {
    f4 r;
    asm volatile("global_load_dwordx4 %0, %1, off" : "=v"(r) : "v"(p));
    return r;
}
__device__ __forceinline__ void st_coh_f4(float* p, f4 v) {
    asm volatile("global_store_dwordx4 %0, %1, off sc0 sc1" :: "v"(p), "v"(v) : "memory");
}
__device__ __forceinline__ void st_coh_u32(unsigned* p, unsigned v) {
    asm volatile("global_store_dword %0, %1, off sc0 sc1" :: "v"(p), "v"(v) : "memory");
}
__device__ __forceinline__ unsigned uload(const unsigned* p) {
    return __hip_atomic_load(p, __ATOMIC_RELAXED, __HIP_MEMORY_SCOPE_AGENT);
}
__device__ __forceinline__ void ustore(unsigned* p, unsigned v) {
    __hip_atomic_store(p, v, __ATOMIC_RELAXED, __HIP_MEMORY_SCOPE_AGENT);
}

#define SBAR()  { __builtin_amdgcn_s_barrier(); __builtin_amdgcn_sched_barrier(0); }
#define LGKM0() { asm volatile("s_waitcnt lgkmcnt(0)" ::: "memory"); __builtin_amdgcn_sched_barrier(0); }
#define VMW(N)  { asm volatile("s_waitcnt vmcnt(" #N ")" ::: "memory"); __builtin_amdgcn_sched_barrier(0); }
#define VMW0_WAVE() { asm volatile("s_waitcnt vmcnt(0)" ::: "memory"); }

// Spin until *p >= target. Sticky timeout -> bugs give wrong answers, not hangs.
__device__ __forceinline__ unsigned spin_ge(const unsigned* p, unsigned target, bool* dead) {
    unsigned v = uload(p);
    if (v >= target || *dead) return v;
    unsigned it = 0;
    while ((v = uload(p)) < target) {
        __builtin_amdgcn_s_sleep(1);
        if (++it > (1u << 20)) { *dead = true; break; }
    }
    return v;
}

// FMA phase: every thread, 64 MACs from LDS-broadcast h times register weights.
__device__ __forceinline__ void fma_phase(const float* hbase, const f4* w,
                                          float* part, int tid, int c4) {
    f2 acc = (f2)0.f;
    const f4* hb4 = (const f4*)hbase;
    #pragma unroll
    for (int i = 0; i < 16; ++i) {
        f4 v = hb4[c4 * 16 + i];
        f4 wi = w[i];
        acc = wi.xy * v.xy + acc;
        acc = wi.zw * v.zw + acc;
    }
    part[tid] = acc.x + acc.y;
}

// ---------------------------------------------------------------------------
// Kernel 1: input projection P[c][t][j] = sum_k Wih0_c[j,k] * x[t,k,c]
__global__ __launch_bounds__(1024) void proj_kernel(
    const float* __restrict__ x, const float* __restrict__ Wlp,
    const float* __restrict__ Wlpv, float* __restrict__ P)
{
    __shared__ float xs[TPB][4][NITEMS];   // 32 KB
    const int tid = threadIdx.x;
    const int t0 = blockIdx.x * TPB;

    #pragma unroll
    for (int tt = 0; tt < TPB; ++tt) {
        const float2* src = (const float2*)(x + (size_t)(t0 + tt) * NITEMS * 4);
        float2 v = src[tid];
        int e = 2 * tid;
        xs[tt][e & 3][e >> 2]       = v.x;
        xs[tt][(e + 1) & 3][e >> 2] = v.y;
    }
    __syncthreads();

    const int c = tid >> 8, j = tid & 255;
    const float* W = (c == 1) ? Wlpv : Wlp;
    const float4* row = (const float4*)(W + (size_t)j * NITEMS);
    float acc[TPB] = {0.f, 0.f, 0.f, 0.f};
    #pragma unroll 4
    for (int k4 = 0; k4 < NITEMS / 4; ++k4) {
        float4 w = row[k4];
        #pragma unroll
        for (int tt = 0; tt < TPB; ++tt) {
            float4 xv = *(const float4*)(&xs[tt][c][k4 * 4]);
            acc[tt] = fmaf(w.x, xv.x, fmaf(w.y, xv.y, fmaf(w.z, xv.z, fmaf(w.w, xv.w, acc[tt]))));
        }
    }
    #pragma unroll
    for (int tt = 0; tt < TPB; ++tt)
        P[((size_t)c * SEQL + (t0 + tt)) * HID + j] = acc[tt];
}

// ---------------------------------------------------------------------------
// One B timestep. Wave0 vmem order per step k: S(k), L(k+2), F(k>0).
// Early-poll on wave4 (tid 256/257): issue flag loads BEFORE the FMA, check
// after -> cross-die poll latency hides under the 512-cyc FMA phase.
#define B_STEP(T_, AREG, VN) {                                                  \
    const int t_ = (T_);                                                        \
    unsigned afv = 0xFFFFFFFFu, bpv = 0xFFFFFFFFu;                              \
    const bool needAf = has_af && (t_ + 2 < SEQL);                              \
    const bool needBp = ((t_ & 7) == 0) && (t_ >= QS);                          \
    if (tid == 256 && needAf)                                                   \
        asm volatile("global_load_dword %0, %1, off sc0 sc1" : "=v"(afv) : "v"(af)); \
    if (tid == 257 && needBp)                                                   \
        asm volatile("global_load_dword %0, %1, off sc0 sc1" : "=v"(bpv) : "v"(consProgA)); \
    fma_phase(hhA[0], w, part, tid, c4);                                        \
    if (tid == 256 && needAf) {                                                 \
        VMW0_WAVE();                                                            \
        if (afv < (unsigned)(t_ + 3)) spin_ge(af, (unsigned)(t_ + 3), &dead);   \
    }                                                                           \
    if (tid == 257 && needBp) {                                                 \
        VMW0_WAVE();                                                            \
        if (bpv < (unsigned)(t_ - 56)) spin_ge(consProgA, (unsigned)(t_ - 56), &dead); \
    }                                                                           \
    if (tid == 320 && has_af && (t_ & 7) == 0 && t_ > 0)                        \
        ustore(myprogB, (unsigned)t_);                                          \
    LGKM0(); SBAR();                                                            \
    if (tid < 64) {                                                             \
        VMW(VN);                                                                \
        const f4* pq = (const f4*)part;                                         \
        f4 s = pq[tid] + pq[64 + tid] + pq[128 + tid] + pq[192 + tid];          \
        f4 tot = s + AREG + bias4;                                              \
        f4 h4;                                                                  \
        h4.x = tanhf(tot.x); h4.y = tanhf(tot.y);                               \
        h4.z = tanhf(tot.z); h4.w = tanhf(tot.w);                               \
        ((f4*)hhA[0])[tid] = h4;                                                \
        st_coh_f4(Hout + (size_t)(t_ & (QS - 1)) * HID + 4 * tid, h4);          \
        if (is_top && t_ == SEQL - 1) *(f4*)(hfin + 4 * tid) = h4;              \
        if (t_ + 2 < SEQL) {                                                    \
            AREG = l0 ? ld_plain_f4(Psrc + (size_t)(t_ + 2) * HID + 4 * tid)    \
                      : ld_coh_f4(ap + (size_t)((t_ + 2) & (QS - 1)) * HID + 4 * tid); \
        }                                                                       \
        LGKM0();                                                                \
    }                                                                           \
    SBAR();                                                                     \
    if (tid == 0 && t_ > 0) st_coh_u32(myHfl, (unsigned)t_);                    \
}

// One A timestep. Wave0 vmem order per step k: S(k), L(k+3), F(k>0).
#define A_STEP(T_, PREG, VN) {                                                  \
    const int t_ = (T_);                                                        \
    unsigned inv = 0xFFFFFFFFu, bpv = 0xFFFFFFFFu;                              \
    const bool needIn = (t_ + 3 < SEQL);                                        \
    const bool needBp = ((t_ & 7) == 0) && (t_ >= QS);                          \
    if (tid == 256 && needIn)                                                   \
        asm volatile("global_load_dword %0, %1, off sc0 sc1" : "=v"(inv) : "v"(inflag)); \
    if (tid == 257 && needBp)                                                   \
        asm volatile("global_load_dword %0, %1, off sc0 sc1" : "=v"(bpv) : "v"(consProgB)); \
    fma_phase(hhA[(T_) & 1], w, part, tid, c4);                                 \
    if (tid == 256 && needIn) {                                                 \
        VMW0_WAVE();                                                            \
        if (inv < (unsigned)(t_ + 4)) spin_ge(inflag, (unsigned)(t_ + 4), &dead); \
    }                                                                           \
    if (tid == 257 && needBp) {                                                 \
        VMW0_WAVE();                                                            \
        if (bpv < (unsigned)(t_ - 56)) spin_ge(consProgB, (unsigned)(t_ - 56), &dead); \
    }                                                                           \
    if (tid == 320 && (t_ & 7) == 0 && t_ > 0)                                  \
        ustore(myprogA, (unsigned)t_);                                          \
    LGKM0(); SBAR();                                                            \
    if (tid < 64) {                                                             \
        VMW(VN);                                                                \
        const f4* pq = (const f4*)part;                                         \
        f4 s = pq[tid] + pq[64 + tid] + pq[128 + tid] + pq[192 + tid];          \
        st_coh_f4(Aout + (size_t)(t_ & (QS - 1)) * HID + 4 * tid, s);           \
        if (t_ + 1 < SEQL) ((f4*)hhA[(t_ + 1) & 1])[tid] = PREG;                \
        if (t_ + 3 < SEQL)                                                      \
            PREG = ld_coh_f4(Hin + (size_t)((t_ + 3) & (QS - 1)) * HID + 4 * tid); \
        LGKM0();                                                                \
    }                                                                           \
    SBAR();                                                                     \
    if (tid == 0 && t_ > 0) st_coh_u32(myAfl, (unsigned)t_);                    \
}

// ---------------------------------------------------------------------------
// Kernel 2: layer-pipelined RNN. 124 blocks = 4 chains x (16 B + 15 A).
__global__ __launch_bounds__(1024) void rnn_pipe(
    const float* __restrict__ lp_Wih,  const float* __restrict__ lp_Whh,
    const float* __restrict__ lp_bih,  const float* __restrict__ lp_bhh,
    const float* __restrict__ lpv_Wih, const float* __restrict__ lpv_Whh,
    const float* __restrict__ lpv_bih, const float* __restrict__ lpv_bhh,
    const float* __restrict__ P, float* __restrict__ Hring,
    float* __restrict__ Apart, float* __restrict__ hfinal,
    unsigned* __restrict__ Hflag, unsigned* __restrict__ Aflag,
    unsigned* __restrict__ progA, unsigned* __restrict__ progB)
{
    __shared__ float hhA[2][HID];
    __shared__ float part[1024];

    const int b = blockIdx.x;
    if (b >= 124) return;
    const int c = b / 31;
    const int r = b % 31;
    const int role = (r < NLAY) ? 0 : 1;            // 0 = B, 1 = A
    const int l = (r < NLAY) ? r : (r - NLAY + 1);  // A covers l = 1..15

    const float* Wih = (c == 1) ? lpv_Wih : lp_Wih;
    const float* Whh = (c == 1) ? lpv_Whh : lp_Whh;
    const float* bih = (c == 1) ? lpv_bih : lp_bih;
    const float* bhh = (c == 1) ? lpv_bhh : lp_bhh;

    const int tid = threadIdx.x;
    const int j = tid & 255, c4 = tid >> 8;   // c4 wave-group-uniform
    bool dead = false;

    if (role == 0) {
        // ===================== B role =====================
        const bool l0     = (l == 0);
        const bool has_af = (l > 0);
        const bool is_top = (l == NLAY - 1);

        f4 w[16];
        f4 pad[4];                        // occupancy control: force >64 VGPR
        {
            const f4* wrow = (const f4*)(Whh + ((size_t)l * HID + j) * HID + (size_t)c4 * 64);
            #pragma unroll
            for (int i = 0; i < 16; ++i) w[i] = wrow[i];
            #pragma unroll
            for (int i = 0; i < 4; ++i) pad[i] = wrow[i];
        }
        #pragma unroll
        for (int i = 0; i < 16; ++i) asm volatile("" : "+v"(w[i]));
        #pragma unroll
        for (int i = 0; i < 4; ++i) asm volatile("" : "+v"(pad[i]));

        f4 bias4 = (f4)0.f;
        if (tid < 64) {
            bias4 = *(const f4*)(bih + l * HID + 4 * tid);
            bias4 += *(const f4*)(bhh + l * HID + 4 * tid);
        }

        const float*    Psrc     = P + (size_t)c * SEQL * HID;
        const float*    ap       = Apart + ((size_t)(c * NLAY + l) * QS) * HID;
        const unsigned* af       = Aflag + c * NLAY + l;
        unsigned*       myHfl    = Hflag + c * NLAY + l;
        unsigned*       myprogB  = progB + c * NLAY + l;
        const unsigned* consProgA = (l < NLAY - 1) ? (progA + c * NLAY + l + 1)
                                                   : (const unsigned*)myprogB;
        float*          Hout     = Hring + ((size_t)(c * NLAY + l) * QS) * HID;
        float*          hfin     = hfinal + (size_t)c * HID;

        // prologue: h(-1)=0; legality for L(0),L(1); issue both prefetches
        if (tid < 256) hhA[0][tid] = 0.f;
        if (has_af && tid == 256) spin_ge(af, 2u, &dead);
        LGKM0(); SBAR();
        f4 a0e = (f4)0.f, a0o = (f4)0.f;
        if (tid < 64) {
            a0e = l0 ? ld_plain_f4(Psrc + 4 * tid)       : ld_coh_f4(ap + 4 * tid);
            a0o = l0 ? ld_plain_f4(Psrc + HID + 4 * tid) : ld_coh_f4(ap + HID + 4 * tid);
        }

        B_STEP(0, a0e, 1);
        B_STEP(1, a0o, 2);
        B_STEP(2, a0e, 3);
        B_STEP(3, a0o, 4);
        for (int t2 = 4; t2 < SEQL - 4; t2 += 2) {
            B_STEP(t2,     a0e, 4);
            B_STEP(t2 + 1, a0o, 4);
        }
        B_STEP(SEQL - 4, a0e, 4);
        B_STEP(SEQL - 3, a0o, 4);
        B_STEP(SEQL - 2, a0e, 4);
        B_STEP(SEQL - 1, a0o, 3);

        if (tid < 64) { VMW(0); }
        SBAR();
        if (tid == 0) st_coh_u32(myHfl, (unsigned)SEQL);
        #pragma unroll
        for (int i = 0; i < 4; ++i) asm volatile("" :: "v"(pad[i]));
    } else {
        // ===================== A role =====================
        f4 w[16];
        f4 pad[4];
        {
            const f4* wrow = (const f4*)(Wih + ((size_t)(l - 1) * HID + j) * HID + (size_t)c4 * 64);
            #pragma unroll
            for (int i = 0; i < 16; ++i) w[i] = wrow[i];
            #pragma unroll
            for (int i = 0; i < 4; ++i) pad[i] = wrow[i];
        }
        #pragma unroll
        for (int i = 0; i < 16; ++i) asm volatile("" : "+v"(w[i]));
        #pragma unroll
        for (int i = 0; i < 4; ++i) asm volatile("" : "+v"(pad[i]));

        const float*    Hin       = Hring + ((size_t)(c * NLAY + (l - 1)) * QS) * HID;
        const unsigned* inflag    = Hflag + c * NLAY + (l - 1);
        float*          Aout      = Apart + ((size_t)(c * NLAY + l) * QS) * HID;
        unsigned*       myAfl     = Aflag + c * NLAY + l;
        unsigned*       myprogA   = progA + c * NLAY + l;
        const unsigned* consProgB = progB + c * NLAY + l;

        // prologue: issue L(0),L(1),L(2); consume L(0) -> hh[0]
        if (tid == 256) spin_ge(inflag, 3u, &dead);
        SBAR();
        f4 pvE = (f4)0.f, pvO = (f4)0.f;
        if (tid < 64) {
            f4 tmp = ld_coh_f4(Hin + 4 * tid);
            pvO = ld_coh_f4(Hin + (size_t)1 * HID + 4 * tid);
            pvE = ld_coh_f4(Hin + (size_t)2 * HID + 4 * tid);
            VMW(2);
            ((f4*)hhA[0])[tid] = tmp;
            LGKM0();
        }
        SBAR();

        A_STEP(0, pvO, 1);
        A_STEP(1, pvE, 2);
        A_STEP(2, pvO, 3);
        A_STEP(3, pvE, 4);
        for (int t2 = 4; t2 < SEQL - 4; t2 += 2) {
            A_STEP(t2,     pvO, 4);
            A_STEP(t2 + 1, pvE, 4);
        }
        A_STEP(SEQL - 4, pvO, 4);
        A_STEP(SEQL - 3, pvE, 4);
        A_STEP(SEQL - 2, pvO, 3);
        A_STEP(SEQL - 1, pvE, 0);

        if (tid < 64) { VMW(0); }
        SBAR();
        if (tid == 0) st_coh_u32(myAfl, (unsigned)SEQL);
        #pragma unroll
        for (int i = 0; i < 4; ++i) asm volatile("" :: "v"(pad[i]));
    }
}

// ---------------------------------------------------------------------------
// Kernel 3: out = fc_W @ concat(h0..h3) + fc_b
__global__ __launch_bounds__(1024) void fc_kernel(
    const float* __restrict__ hfinal, const float* __restrict__ fcW,
    const float* __restrict__ fcb, float* __restrict__ out)
{
    __shared__ float red[1024];
    const int tid = threadIdx.x;
    float v  = hfinal[tid];
    float p0 = fcW[tid] * v;
    float p1 = fcW[1024 + tid] * v;

    red[tid] = p0; __syncthreads();
    for (int st = 512; st > 0; st >>= 1) { if (tid < st) red[tid] += red[tid + st]; __syncthreads(); }
    if (tid == 0) out[0] = red[0] + fcb[0];
    __syncthreads();
    red[tid] = p1; __syncthreads();
    for (int st = 512; st > 0; st >>= 1) { if (tid < st) red[tid] += red[tid + st]; __syncthreads(); }
    if (tid == 0) out[1] = red[0] + fcb[1];
}

// ---------------------------------------------------------------------------
extern "C" void kernel_launch(void* const* d_in, const int* in_sizes, int n_in,
                              void* d_out, int out_size, void* d_ws, size_t ws_size,
                              hipStream_t stream)
{
    (void)in_sizes; (void)n_in; (void)out_size; (void)ws_size;
    const float* x        = (const float*)d_in[0];
    const float* lp_Wih0  = (const float*)d_in[1];
    const float* lp_Wih   = (const float*)d_in[2];
    const float* lp_Whh   = (const float*)d_in[3];
    const float* lp_bih   = (const float*)d_in[4];
    const float* lp_bhh   = (const float*)d_in[5];
    const float* lpv_Wih0 = (const float*)d_in[6];
    const float* lpv_Wih  = (const float*)d_in[7];
    const float* lpv_Whh  = (const float*)d_in[8];
    const float* lpv_bih  = (const float*)d_in[9];
    const float* lpv_bhh  = (const float*)d_in[10];
    const float* fcW      = (const float*)d_in[11];
    const float* fcb      = (const float*)d_in[12];

    float* ws      = (float*)d_ws;
    float* Pbuf    = ws + P_OFF;
    float* Hring   = ws + H_OFF;
    float* Apart   = ws + AP_OFF;
    float* hfinal  = ws + HF_OFF;
    unsigned* flags = (unsigned*)(ws + FLAG_OFF_FLOATS);

    hipMemsetAsync(flags, 0, NFLAGS * sizeof(unsigned), stream);

    proj_kernel<<<SEQL / TPB, 1024, 0, stream>>>(x, lp_Wih0, lpv_Wih0, Pbuf);

    rnn_pipe<<<124, 1024, 0, stream>>>(lp_Wih, lp_Whh, lp_bih, lp_bhh,
                                       lpv_Wih, lpv_Whh, lpv_bih, lpv_bhh,
                                       Pbuf, Hring, Apart, hfinal,
                                       flags, flags + 64, flags + 128, flags + 192);

    fc_kernel<<<1, 1024, 0, stream>>>(hfinal, fcW, fcb, (float*)d_out);
}